// Round 9
// baseline (157.694 us; speedup 1.0000x reference)
//
#include <hip/hip_runtime.h>
#include <stdint.h>

// ---- types ----
typedef _Float16 f16x8 __attribute__((ext_vector_type(8)));
typedef _Float16 f16x4 __attribute__((ext_vector_type(4)));
typedef _Float16 f16v2 __attribute__((ext_vector_type(2)));
typedef __fp16 h16x2 __attribute__((ext_vector_type(2)));  // cvt_pkrtz return type
typedef float f32x4 __attribute__((ext_vector_type(4)));

#define SEQ 2048
#define NHEADS 8

// async global->LDS, 16B per lane, LDS dest = wave-uniform base + lane*16
#define GLOAD_LDS16(gp, lp)                                                        \
  __builtin_amdgcn_global_load_lds(                                                \
      (const __attribute__((address_space(1))) void*)(uintptr_t)(const void*)(gp), \
      (__attribute__((address_space(3))) void*)(uintptr_t)(void*)(lp), 16, 0, 0)

// barrier that waits LDS ops only (no vmem drain)
__device__ __forceinline__ void barrier_lds() {
  __builtin_amdgcn_s_waitcnt(0xc07f);  // lgkmcnt(0)
  __builtin_amdgcn_s_barrier();
}

__device__ __forceinline__ f16x4 pack4(float a, float b, float c, float d) {
  h16x2 lo = __builtin_amdgcn_cvt_pkrtz(a, b);
  h16x2 hi = __builtin_amdgcn_cvt_pkrtz(c, d);
  f16x4 o;
  o.x = (_Float16)lo.x; o.y = (_Float16)lo.y;
  o.z = (_Float16)hi.x; o.w = (_Float16)hi.y;
  return o;
}

// ---------------- fp32 -> f16 convert (x + 4 weights, one launch) ----------------
__global__ void cvt_all_kernel(const float* __restrict__ x, const float* __restrict__ wq,
                               const float* __restrict__ wk, const float* __restrict__ wv,
                               const float* __restrict__ wo, _Float16* __restrict__ xh,
                               _Float16* __restrict__ wh) {
  int i = blockIdx.x * 256 + threadIdx.x;  // 0 .. 1310719 (f4 units)
  const float* src;
  _Float16* dst;
  int off;
  if (i < 1048576) {
    src = x; dst = xh; off = i;
  } else {
    int j = i - 1048576;
    int sel = j >> 16;
    off = j & 65535;
    src = (sel == 0) ? wq : (sel == 1) ? wk : (sel == 2) ? wv : wo;
    dst = wh + (size_t)sel * 262144;
  }
  float4 v = ((const float4*)src)[off];
  ((f16x4*)dst)[off] = pack4(v.x, v.y, v.z, v.w);
}

// ---------------- shared 128x128 B^T GEMM tile core (f16, single-buffered) ----------------
__device__ __forceinline__ void gemm_tile_bt(const _Float16* __restrict__ A,
                                             const _Float16* __restrict__ B,
                                             int m0, int n0,
                                             _Float16* As, _Float16* Bs,
                                             f32x4 (&acc)[4][4]) {
  const int tid = threadIdx.x;
  const int w = tid >> 6, lane = tid & 63;
  const int wr = w >> 1, wc = w & 1;
  const int lrow = lane & 15, q = lane >> 4;
  const int snb = w * 32 + (lane >> 3);
  const int scb = lane & 7;

#pragma unroll
  for (int i = 0; i < 4; ++i)
#pragma unroll
    for (int j = 0; j < 4; ++j)
#pragma unroll
      for (int r = 0; r < 4; ++r) acc[i][j][r] = 0.f;

  for (int kt = 0; kt < 8; ++kt) {  // K=512, BK=64
    __syncthreads();
#pragma unroll
    for (int t = 0; t < 4; ++t) {
      int n = snb + t * 8;
      int cbg = scb ^ (n & 7);
      GLOAD_LDS16(A + (size_t)(m0 + n) * 512 + kt * 64 + cbg * 8,
                  As + (w * 32 + t * 8) * 64);
      GLOAD_LDS16(B + (size_t)(n0 + n) * 512 + kt * 64 + cbg * 8,
                  Bs + (w * 32 + t * 8) * 64);
    }
    __syncthreads();

    f16x8 af[4][2], bfr[4][2];
#pragma unroll
    for (int i = 0; i < 4; ++i) {
      int m = wr * 64 + i * 16 + lrow;
#pragma unroll
      for (int kk = 0; kk < 2; ++kk) {
        int cb = (kk * 4 + q) ^ (m & 7);
        af[i][kk] = *(const f16x8*)(As + m * 64 + cb * 8);
      }
    }
#pragma unroll
    for (int j = 0; j < 4; ++j) {
      int n = wc * 64 + j * 16 + lrow;
#pragma unroll
      for (int kk = 0; kk < 2; ++kk) {
        int cb = (kk * 4 + q) ^ (n & 7);
        bfr[j][kk] = *(const f16x8*)(Bs + n * 64 + cb * 8);
      }
    }
#pragma unroll
    for (int i = 0; i < 4; ++i)
#pragma unroll
      for (int j = 0; j < 4; ++j) {
        acc[i][j] = __builtin_amdgcn_mfma_f32_16x16x32_f16(af[i][0], bfr[j][0], acc[i][j], 0, 0, 0);
        acc[i][j] = __builtin_amdgcn_mfma_f32_16x16x32_f16(af[i][1], bfr[j][1], acc[i][j], 0, 0, 0);
      }
  }
}

// ---------------- QKV projection: 768 blocks, 3/CU co-resident ----------------
// z=0 folds the attention scale c1=(1/8)*log2(e) into Q.
__global__ __launch_bounds__(256, 3) void qkv_kernel(
    const _Float16* __restrict__ xb, const _Float16* __restrict__ Wq,
    const _Float16* __restrict__ Wk, const _Float16* __restrict__ Wv,
    _Float16* __restrict__ Qo, _Float16* __restrict__ Ko, _Float16* __restrict__ Vto) {
  __shared__ _Float16 pool[17408];  // 34.8 KB: staging (32KB) then bounce [128][136]
  _Float16* As = pool;
  _Float16* Bs = pool + 8192;
  const int z = blockIdx.z;
  f32x4 acc[4][4];
  const int tid = threadIdx.x, w = tid >> 6, lane = tid & 63;
  const int wr = w >> 1, wc = w & 1, lcol = lane & 15, q = lane >> 4;

  if (z < 2) {
    const int m0 = blockIdx.y * 128;  // out-feature tile
    const int n0 = blockIdx.x * 128;  // s tile
    gemm_tile_bt((z == 0) ? Wq : Wk, xb, m0, n0, As, Bs, acc);
    const float sc = (z == 0) ? 0.18033688011112042f : 1.0f;  // fold qk-scale into Q
    _Float16* outp = (z == 0) ? Qo : Ko;
    __syncthreads();  // staging reads done; reuse pool as bounce [s 128][c 136]
#pragma unroll
    for (int i = 0; i < 4; ++i) {
      int cl = wr * 64 + i * 16 + q * 4;
#pragma unroll
      for (int j = 0; j < 4; ++j) {
        int s = wc * 64 + j * 16 + lcol;
        *(f16x4*)(pool + s * 136 + cl) =
            pack4(acc[i][j][0] * sc, acc[i][j][1] * sc, acc[i][j][2] * sc, acc[i][j][3] * sc);
      }
    }
    __syncthreads();
#pragma unroll
    for (int it = 0; it < 16; ++it) {
      int srow = it * 8 + (tid >> 5);
      int ch = tid & 31;
      f16x4 v = *(const f16x4*)(pool + srow * 136 + ch * 4);
      *(f16x4*)(outp + (size_t)(n0 + srow) * 512 + m0 + ch * 4) = v;
    }
  } else {
    const int m0 = blockIdx.x * 128;  // s tile
    const int n0 = blockIdx.y * 128;  // feature tile
    gemm_tile_bt(xb, Wv, m0, n0, As, Bs, acc);
    const int bb = m0 >> 11, sl0 = m0 & 2047;
    __syncthreads();  // bounce [c 128][s 136]
#pragma unroll
    for (int i = 0; i < 4; ++i) {
      int s0 = wr * 64 + i * 16 + q * 4;
#pragma unroll
      for (int j = 0; j < 4; ++j) {
        int c = wc * 64 + j * 16 + lcol;
        *(f16x4*)(pool + c * 136 + s0) =
            pack4(acc[i][j][0], acc[i][j][1], acc[i][j][2], acc[i][j][3]);
      }
    }
    __syncthreads();
#pragma unroll
    for (int it = 0; it < 16; ++it) {
      int crow = it * 8 + (tid >> 5);
      int ch = tid & 31;
      int cg = n0 + crow, h = cg >> 6, d = cg & 63;
      f16x4 v = *(const f16x4*)(pool + crow * 136 + ch * 4);
      *(f16x4*)(Vto + ((size_t)((bb * NHEADS + h) * 64 + d)) * SEQ + sl0 + ch * 4) = v;
    }
  }
}

// ---------------- sigmoid attention: q64/k64 tiles, 4 blocks/CU, register P ----------------
// Wave owns 16 q-rows. 32 KB LDS dbuf (Ks[64][64] + Vts[64][64] per buf), 1 barrier/kt.
// Q pre-scaled by (1/8)log2e: u=exp2(s); w=u*2^-11; P'=u*(1-w+w^2)=2048*sigmoid.
__global__ __launch_bounds__(256, 4) void attn_kernel(
    const _Float16* __restrict__ Qw, const _Float16* __restrict__ Kw,
    const _Float16* __restrict__ Vtw, _Float16* __restrict__ Ow) {
  __shared__ _Float16 lds[16384];  // 32 KB: buf b at lds+b*8192: Ks 4096, Vts 4096

  const int tid = threadIdx.x, w = tid >> 6, lane = tid & 63;
  const int lrow = lane & 15, q = lane >> 4;

  // XCD swizzle: 4 bh x 32 q-tiles per XCD (K/V stay L2-resident per XCD)
  const int L = blockIdx.x;
  const int xcd = L & 7, slot = L >> 3;
  const int bh = xcd * 4 + (slot >> 5), qt = slot & 31;
  const int b = bh >> 3, h = bh & 7;
  const int q0 = qt * 64;

  const _Float16* Qp = Qw + ((size_t)(b * SEQ + q0)) * 512 + h * 64;
  const _Float16* Kp = Kw + ((size_t)b * SEQ) * 512 + h * 64;
  const _Float16* Vp = Vtw + (size_t)bh * 64 * SEQ;

  const int sr = w * 16 + (lane >> 3);  // staging row (+t*8)
  const int scb = lane & 7;

  // stage Q tile [64][64] into lds[0..4096)
#pragma unroll
  for (int t = 0; t < 2; ++t) {
    int row = sr + t * 8;
    int cbg = scb ^ (row & 7);
    GLOAD_LDS16(Qp + (size_t)row * 512 + cbg * 8, lds + (w * 16 + t * 8) * 64);
  }
  __syncthreads();

  // wave's 16 q-rows
  f16x8 qa[2];
  {
    int m = w * 16 + lrow;
#pragma unroll
    for (int kk = 0; kk < 2; ++kk)
      qa[kk] = *(const f16x8*)(lds + m * 64 + (((kk * 4 + q) ^ (m & 7)) << 3));
  }
  barrier_lds();  // all qa reads done before buf0 DMA overwrite

  // issue kt=0 staging into buf0
#pragma unroll
  for (int t = 0; t < 2; ++t) {
    int row = sr + t * 8;
    int cbg = scb ^ (row & 7);
    GLOAD_LDS16(Kp + (size_t)row * 512 + cbg * 8, lds + (w * 16 + t * 8) * 64);
    GLOAD_LDS16(Vp + (size_t)row * SEQ + cbg * 8, lds + 4096 + (w * 16 + t * 8) * 64);
  }

  f32x4 oacc[4];
#pragma unroll
  for (int j = 0; j < 4; ++j)
#pragma unroll
    for (int r = 0; r < 4; ++r) oacc[j][r] = 0.f;

  const f16v2 c2 = {(_Float16)4.8828125e-4f, (_Float16)4.8828125e-4f};  // 2^-11

  for (int kt = 0; kt < 32; ++kt) {
    __syncthreads();  // kt's DMA landed (issued one iter ago); prev buf reads done
    if (kt < 31) {
      _Float16* nb = lds + ((kt + 1) & 1) * 8192;
#pragma unroll
      for (int t = 0; t < 2; ++t) {
        int row = sr + t * 8;
        int cbg = scb ^ (row & 7);
        GLOAD_LDS16(Kp + (size_t)((kt + 1) * 64 + row) * 512 + cbg * 8, nb + (w * 16 + t * 8) * 64);
        GLOAD_LDS16(Vp + (size_t)row * SEQ + (kt + 1) * 64 + cbg * 8, nb + 4096 + (w * 16 + t * 8) * 64);
      }
    }
    const _Float16* Ksc = lds + (kt & 1) * 8192;
    const _Float16* Vtsc = Ksc + 4096;

    // per 16-kcol block j: S^T via K=32 MFMA -> packed-f16 sigmoid -> PV via K=16
#pragma unroll
    for (int j = 0; j < 4; ++j) {
      int n = j * 16 + lrow;
      f16x8 k0 = *(const f16x8*)(Ksc + n * 64 + ((q ^ (n & 7)) << 3));
      f16x8 k1 = *(const f16x8*)(Ksc + n * 64 + (((4 + q) ^ (n & 7)) << 3));
      f32x4 s;
#pragma unroll
      for (int r = 0; r < 4; ++r) s[r] = 0.f;
      s = __builtin_amdgcn_mfma_f32_16x16x32_f16(k0, qa[0], s, 0, 0, 0);
      s = __builtin_amdgcn_mfma_f32_16x16x32_f16(k1, qa[1], s, 0, 0, 0);

      // sigmoid (scaled x2048): u = 2^s; w = u*2^-11; p = u*(1 - w + w^2)
      float u0 = __builtin_amdgcn_exp2f(s[0]);
      float u1 = __builtin_amdgcn_exp2f(s[1]);
      float u2 = __builtin_amdgcn_exp2f(s[2]);
      float u3 = __builtin_amdgcn_exp2f(s[3]);
      f16v2 ua = __builtin_bit_cast(f16v2, __builtin_amdgcn_cvt_pkrtz(u0, u1));
      f16v2 ub = __builtin_bit_cast(f16v2, __builtin_amdgcn_cvt_pkrtz(u2, u3));
      f16v2 wa = ua * c2, wb = ub * c2;
      f16v2 ta = wa * wa - wa, tb = wb * wb - wb;
      f16v2 pa2 = ua * ta + ua, pb2 = ub * tb + ub;
      f16x4 pf;
      pf.x = pa2.x; pf.y = pa2.y; pf.z = pb2.x; pf.w = pb2.y;

      // PV: O[qrow][d] += P * V^T; B-frag b64 reads, swizzle-matched
#pragma unroll
      for (int j2 = 0; j2 < 4; ++j2) {
        int nv = j2 * 16 + lrow;
        int kbs = (j * 2 + (q >> 1)) ^ (nv & 7);
        f16x4 vb = *(const f16x4*)(Vtsc + nv * 64 + (kbs << 3) + ((q & 1) << 2));
        oacc[j2] = __builtin_amdgcn_mfma_f32_16x16x16f16(pf, vb, oacc[j2], 0, 0, 0);
      }
    }
  }

  // epilogue: descale 2^-11, bounce [64][72] in buf0 region, coalesced 128B stores
  _Float16* Ob = lds;  // buf0 (kt=31 used buf1; buf0 reads finished before kt=31 barrier)
#pragma unroll
  for (int j2 = 0; j2 < 4; ++j2) {
    int d = j2 * 16 + lrow;
#pragma unroll
    for (int r = 0; r < 4; ++r) {
      int row = w * 16 + q * 4 + r;
      Ob[row * 72 + d] = (_Float16)(oacc[j2][r] * 4.8828125e-4f);
    }
  }
  barrier_lds();
#pragma unroll
  for (int it = 0; it < 4; ++it) {
    int row = it * 16 + (tid >> 4);
    int ch = tid & 15;
    f16x4 v = *(const f16x4*)(Ob + row * 72 + ch * 4);
    *(f16x4*)(Ow + (size_t)(b * SEQ + q0 + row) * 512 + h * 64 + ch * 4) = v;
  }
}

// ---------------- output projection (fp32 out, coalesced) ----------------
__global__ __launch_bounds__(256, 2) void oproj_kernel(
    const _Float16* __restrict__ A, const _Float16* __restrict__ Wo,
    float* __restrict__ out) {
  __shared__ _Float16 pool[16384];  // 32 KB staging
  const int m0 = blockIdx.x * 128, n0 = blockIdx.y * 128;
  f32x4 acc[4][4];
  gemm_tile_bt(A, Wo, m0, n0, pool, pool + 8192, acc);

  const int tid = threadIdx.x, w = tid >> 6, lane = tid & 63;
  const int wr = w >> 1, wc = w & 1, lcol = lane & 15, q = lane >> 4;
#pragma unroll
  for (int i = 0; i < 4; ++i) {
    int gm0 = m0 + wr * 64 + i * 16 + q * 4;
#pragma unroll
    for (int j = 0; j < 4; ++j) {
      int gn = n0 + wc * 64 + j * 16 + lcol;
#pragma unroll
      for (int r = 0; r < 4; ++r)
        out[(size_t)(gm0 + r) * 512 + gn] = acc[i][j][r];
    }
  }
}

// ---------------- launch ----------------
extern "C" void kernel_launch(void* const* d_in, const int* in_sizes, int n_in,
                              void* d_out, int out_size, void* d_ws, size_t ws_size,
                              hipStream_t stream) {
  const float* x = (const float*)d_in[0];
  const float* Wq = (const float*)d_in[1];
  const float* Wk = (const float*)d_in[2];
  const float* Wv = (const float*)d_in[3];
  const float* Wo = (const float*)d_in[4];
  float* out = (float*)d_out;
  char* ws = (char*)d_ws;

  _Float16* xh = (_Float16*)(ws + 0);          // 8 MB [8192][512]
  _Float16* wh = (_Float16*)(ws + 8388608);    // 4 x 512 KB (q,k,v,o)
  _Float16* Qw = (_Float16*)(ws + 10485760);   // 8 MB [8192][512] (pre-scaled by c1)
  _Float16* Kw = (_Float16*)(ws + 18874368);   // 8 MB [8192][512]
  _Float16* Vtw = (_Float16*)(ws + 27262976);  // 8 MB [B,H,D,S]
  _Float16* Ow = (_Float16*)(ws + 35651584);   // 8 MB [8192][512]

  _Float16* wqh = wh;
  _Float16* wkh = wh + 262144;
  _Float16* wvh = wh + 524288;
  _Float16* woh = wh + 786432;

  cvt_all_kernel<<<5120, 256, 0, stream>>>(x, Wq, Wk, Wv, Wo, xh, wh);
  qkv_kernel<<<dim3(64, 4, 3), 256, 0, stream>>>(xh, wqh, wkh, wvh, Qw, Kw, Vtw);
  attn_kernel<<<1024, 256, 0, stream>>>(Qw, Kw, Vtw, Ow);
  oproj_kernel<<<dim3(64, 4), 256, 0, stream>>>(Ow, woh, out);
}